// Round 15
// baseline (116.635 us; speedup 1.0000x reference)
//
#include <hip/hip_runtime.h>

#define F_IN 128
#define CH   128

typedef __attribute__((ext_vector_type(8))) short bf16x8;
typedef __attribute__((ext_vector_type(4))) float f32x4;
typedef __attribute__((ext_vector_type(2))) float f32x2;
typedef __attribute__((ext_vector_type(2))) unsigned u32x2;

// f32 -> bf16 round-to-nearest-even
static __device__ __forceinline__ ushort f2b(float f) {
  union { float f; unsigned u; } v; v.f = f;
  const unsigned u = v.u;
  return (ushort)((u + 0x7FFFu + ((u >> 16) & 1u)) >> 16);
}

// ---------------------------------------------------------------------------
// Phase 1 (fused): blocks [0, gemm_blocks) do XW = X @ W via bf16 MFMA,
//   then quantize each output row to int8 (offset-binary, per-node scale
//   s[r] = rowmax/127) -> 12.8 MB table + 400 KB scales. 128 rows/block.
//   Quant epilogue via wave-private LDS slab -> coalesced u32x2 stores (R11).
// blocks [gemm_blocks, ...): row_ptr boundary scan, 4 edges/thread (int4).
// mfma_f32_16x16x32_bf16 layouts (guide §3, m89-verified):
//   A frag: row = lane&15, k = (lane>>4)*8 + j
//   B frag: col = lane&15, k = (lane>>4)*8 + j
//   C/D   : col = lane&15, row = (lane>>4)*4 + reg
// ---------------------------------------------------------------------------
__global__ __launch_bounds__(512) void gemm_rowptr_fused(
    const float* __restrict__ x, const float* __restrict__ w,
    unsigned char* __restrict__ xwq, float* __restrict__ scale,
    const int* __restrict__ edge_row, int* __restrict__ row_ptr,
    int n, int n_edges, int gemm_blocks) {
  __shared__ __align__(16) ushort Wt[F_IN * CH];  // W^T, swizzled, 32 KB
  const int t = threadIdx.x;

  if ((int)blockIdx.x >= gemm_blocks) {
    // ---- rowptr tail blocks: boundary scan, 4 edges per thread ----
    const int base = (((int)blockIdx.x - gemm_blocks) * 512 + t) * 4;
    if (base < n_edges) {
      const int4 er = *(const int4*)&edge_row[base];
      const int nxt = (base + 4 < n_edges) ? edge_row[base + 4] : n;
      if (base == 0) {
        for (int r = 0; r <= er.x; ++r) row_ptr[r] = 0;
      }
      for (int r = er.x + 1; r <= er.y; ++r) row_ptr[r] = base + 1;
      for (int r = er.y + 1; r <= er.z; ++r) row_ptr[r] = base + 2;
      for (int r = er.z + 1; r <= er.w; ++r) row_ptr[r] = base + 3;
      for (int r = er.w + 1; r <= nxt;  ++r) row_ptr[r] = base + 4;
    }
    return;
  }

  // ---- GEMM blocks ----
  // stage W^T as bf16 with XOR swizzle: byte ^= (col&7)<<4
  for (int i = t; i < (F_IN * CH) / 4; i += 512) {
    const int k  = i >> 5;          // 0..127
    const int n4 = (i & 31) << 2;   // 0,4,...,124
    const f32x4 wv = *(const f32x4*)&w[k * CH + n4];
#pragma unroll
    for (int q = 0; q < 4; ++q) {
      const int nn = n4 + q;
      const int byte = (nn * 256 + k * 2) ^ ((nn & 7) << 4);
      *(ushort*)((char*)Wt + byte) = f2b(wv[q]);
    }
  }
  __syncthreads();

  const int wave = t >> 6, lane = t & 63;
  const int li   = lane & 15;
  const int kgrp = (lane >> 4) * 8;
  const int R0   = blockIdx.x * 128 + wave * 16;
  const int arow = R0 + li;

  // A fragments (4 K-steps), f32->bf16 in-register; x read-once -> nt loads
  bf16x8 a[4];
#pragma unroll
  for (int s = 0; s < 4; ++s) {
    if (arow < n) {
      const f32x4 p0 = __builtin_nontemporal_load(
          (const f32x4*)&x[arow * F_IN + s * 32 + kgrp]);
      const f32x4 p1 = __builtin_nontemporal_load(
          (const f32x4*)&x[arow * F_IN + s * 32 + kgrp + 4]);
#pragma unroll
      for (int j = 0; j < 4; ++j) {
        a[s][j]     = (short)f2b(p0[j]);
        a[s][j + 4] = (short)f2b(p1[j]);
      }
    } else {
#pragma unroll
      for (int j = 0; j < 8; ++j) a[s][j] = (short)0;
    }
  }

  f32x4 acc[8];
#pragma unroll
  for (int t8 = 0; t8 < 8; ++t8) acc[t8] = (f32x4){0.f, 0.f, 0.f, 0.f};

#pragma unroll
  for (int t8 = 0; t8 < 8; ++t8) {
    const int col = t8 * 16 + li;
#pragma unroll
    for (int s = 0; s < 4; ++s) {
      const int byte = (col * 256 + (s * 32 + kgrp) * 2) ^ ((col & 7) << 4);
      const bf16x8 b = *(const bf16x8*)((const char*)Wt + byte);
      acc[t8] = __builtin_amdgcn_mfma_f32_16x16x32_bf16(a[s], b, acc[t8], 0, 0, 0);
    }
  }

  // Epilogue A: per-row absmax (shfl over 16 channel-lanes) + scale store
  float inv4[4];
  const int r0 = R0 + (lane >> 4) * 4;
#pragma unroll
  for (int i = 0; i < 4; ++i) {
    float m = 0.f;
#pragma unroll
    for (int t8 = 0; t8 < 8; ++t8) m = fmaxf(m, fabsf(acc[t8][i]));
    m = fmaxf(m, __shfl_xor(m, 1));
    m = fmaxf(m, __shfl_xor(m, 2));
    m = fmaxf(m, __shfl_xor(m, 4));
    m = fmaxf(m, __shfl_xor(m, 8));
    inv4[i] = (m > 1e-20f) ? 127.f / m : 0.f;
    const int rr = r0 + i;
    if (rr < n && li == 0) scale[rr] = m * (1.f / 127.f);
  }

  // Epilogue B: quantize through wave-private LDS slab -> coalesced stores.
  __syncthreads();  // all waves done reading Wt; safe to reuse as byte buffer
  unsigned char* qb8 = (unsigned char*)Wt + wave * 2048;  // 16 rows x 128 B
#pragma unroll
  for (int i = 0; i < 4; ++i) {
    const int rl = (lane >> 4) * 4 + i;   // row-local 0..15
#pragma unroll
    for (int t8 = 0; t8 < 8; ++t8) {
      // |acc|*inv <= 127 by construction; +128 -> [1,255], no clamp
      const float q = rintf(acc[t8][i] * inv4[i]) + 128.f;
      qb8[rl * 128 + t8 * 16 + li] = (unsigned char)q;
    }
  }
  // wave-private region: compiler orders ds reads after writes via lgkmcnt
#pragma unroll
  for (int p = 0; p < 4; ++p) {
    const int idx = p * 64 + lane;        // 0..255
    const int rl  = idx >> 4;             // row-local 0..15
    const int off = (idx & 15) * 8;       // byte offset in row
    const int rrow = blockIdx.x * 128 + wave * 16 + rl;
    if (rrow < n) {
      const u32x2 v = *(const u32x2*)&qb8[rl * 128 + off];
      *(u32x2*)&xwq[(size_t)rrow * CH + off] = v;
    }
  }
}

// ---------------------------------------------------------------------------
// Phase 2: SpMM, QUARTER-WAVE per row, 32-edge superblock, 256-thr blocks.
// R15: the 32 gathers are INLINE-ASM global_load_dwordx2 (distinct "=v"
// outputs) + one asm s_waitcnt vmcnt(0) + sched_barrier(0) before decode
// (guide rule #18). Volatile asm order is pinned and every result register
// must live to its decode use -> the allocator MUST hold the full batch:
// per-wave outstanding lines 8 -> 32, the experiment R13 (launch_bounds)
// and R14 (sched_barrier alone) failed to execute (VGPR stayed 40-48).
// Confirmation signal: VGPR >= ~100. Pre-committed falsifier: VGPR>=100
// and time flat => scattered-line latency/queue limit => roofline.
// Rest frozen from R12: quarter-wave (lane li owns ch li*8..li*8+7, no
// cross-lane acc reduction); meta 2 edges/lane nt + scale gather (dummy
// c=0/vp=0); staggered LDS slab; f32x2 pk_fma decode, 8-edge early-exit;
// scalar S quarter-reduce; lane-local epilogue.
// ---------------------------------------------------------------------------
#define ACCD(word, j0, vv)                                                \
  do {                                                                    \
    f32x2 lo_, hi_;                                                       \
    lo_[0] = (float)((word) & 0xFFu);                                     \
    lo_[1] = (float)(((word) >> 8) & 0xFFu);                              \
    hi_[0] = (float)(((word) >> 16) & 0xFFu);                             \
    hi_[1] = (float)((word) >> 24);                                       \
    acc2[(j0)]     = __builtin_elementwise_fma(vv, lo_, acc2[(j0)]);      \
    acc2[(j0) + 1] = __builtin_elementwise_fma(vv, hi_, acc2[(j0) + 1]);  \
  } while (0)

#define ACC8PK(U, V)                                                      \
  do {                                                                    \
    const f32x2 vv_ = {(V), (V)};                                         \
    ACCD((U)[0], 0, vv_);                                                 \
    ACCD((U)[1], 2, vv_);                                                 \
  } while (0)

#define GLD2(dst, ptr)                                                    \
  asm volatile("global_load_dwordx2 %0, %1, off"                          \
               : "=v"(dst) : "v"(ptr))

__global__ __launch_bounds__(256, 4) void spmm_qwave(
    const unsigned char* __restrict__ xwq, const float* __restrict__ scale,
    const float* __restrict__ edge_val, const int* __restrict__ edge_col,
    const int* __restrict__ row_ptr, const float* __restrict__ bias,
    float* __restrict__ out, int n) {
  __shared__ int   cbuf[16 * 40];   // 16 quarters x (32 used + 8 pad)
  __shared__ float vbuf[16 * 40];
  const int tid = threadIdx.x;
  const int row = (int)((blockIdx.x * 256 + tid) >> 4);
  if (row >= n) return;
  const int li = tid & 15;          // lane-in-quarter: owns ch li*8..li*8+7
  const int qb = (tid >> 4) * 40;   // staggered quarter base
  const u32x2* __restrict__ xw2 = (const u32x2*)xwq;  // 16 u32x2 per row

  const int start = row_ptr[row], end = row_ptr[row + 1];

  f32x2 acc2[4];
#pragma unroll
  for (int j = 0; j < 4; ++j) acc2[j] = (f32x2){0.f, 0.f};
  float S = 0.f;  // per-lane sum of vp (offset correction)

  for (int e0 = start; e0 < end; e0 += 32) {
    // meta: 2 edges per lane, independent back-to-back chains
    const int ea = e0 + li, eb = e0 + 16 + li;
    int   c0 = 0, c1 = 0;
    float v0 = 0.f, v1 = 0.f;
    if (ea < end) {
      c0 = __builtin_nontemporal_load(edge_col + ea);
      v0 = __builtin_nontemporal_load(edge_val + ea) * scale[c0];
    }
    if (eb < end) {
      c1 = __builtin_nontemporal_load(edge_col + eb);
      v1 = __builtin_nontemporal_load(edge_val + eb) * scale[c1];
    }
    S += v0 + v1;
    cbuf[qb + li] = c0;  cbuf[qb + 16 + li] = c1;   // wave-private slab:
    vbuf[qb + li] = v0;  vbuf[qb + 16 + li] = v1;   // in-wave DS ordering

    // batch-issue all 32 gathers via volatile asm: issue order pinned,
    // all 32 results forced register-live until decode.
    u32x2 u[32];
#pragma unroll
    for (int it4 = 0; it4 < 8; ++it4) {
      const int4 c4 = *(const int4*)&cbuf[qb + it4 * 4];
      GLD2(u[it4 * 4 + 0], &xw2[c4.x * 16 + li]);
      GLD2(u[it4 * 4 + 1], &xw2[c4.y * 16 + li]);
      GLD2(u[it4 * 4 + 2], &xw2[c4.z * 16 + li]);
      GLD2(u[it4 * 4 + 3], &xw2[c4.w * 16 + li]);
    }
    asm volatile("s_waitcnt vmcnt(0)" ::: "memory");
    __builtin_amdgcn_sched_barrier(0);  // rule #18: fence VALU hoisting

    // decode: early-exit at 8-edge granularity (wave-uniform break)
#pragma unroll
    for (int g = 0; g < 4; ++g) {
      if (e0 + g * 8 >= end) break;
      const f32x4 va = *(const f32x4*)&vbuf[qb + g * 8];
      const f32x4 vb = *(const f32x4*)&vbuf[qb + g * 8 + 4];
      ACC8PK(u[g * 8 + 0], va[0]);
      ACC8PK(u[g * 8 + 1], va[1]);
      ACC8PK(u[g * 8 + 2], va[2]);
      ACC8PK(u[g * 8 + 3], va[3]);
      ACC8PK(u[g * 8 + 4], vb[0]);
      ACC8PK(u[g * 8 + 5], vb[1]);
      ACC8PK(u[g * 8 + 6], vb[2]);
      ACC8PK(u[g * 8 + 7], vb[3]);
    }
  }

  // S over the quarter's 16 lanes (each owned distinct edges)
  S += __shfl_xor(S, 1);
  S += __shfl_xor(S, 2);
  S += __shfl_xor(S, 4);
  S += __shfl_xor(S, 8);

  // epilogue: lane-local 8 channels, bias+ReLU, direct store — no masking
  const float off = 128.f * S;
  const float* a = (const float*)acc2;
  const int cb = li * 8;
  const f32x4 b0 = *(const f32x4*)&bias[cb];
  const f32x4 b1 = *(const f32x4*)&bias[cb + 4];
  f32x4 o0, o1;
  o0[0] = fmaxf(a[0] - off + b0[0], 0.f);
  o0[1] = fmaxf(a[1] - off + b0[1], 0.f);
  o0[2] = fmaxf(a[2] - off + b0[2], 0.f);
  o0[3] = fmaxf(a[3] - off + b0[3], 0.f);
  o1[0] = fmaxf(a[4] - off + b1[0], 0.f);
  o1[1] = fmaxf(a[5] - off + b1[1], 0.f);
  o1[2] = fmaxf(a[6] - off + b1[2], 0.f);
  o1[3] = fmaxf(a[7] - off + b1[3], 0.f);
  __builtin_nontemporal_store(o0, (f32x4*)&out[(size_t)row * CH + cb]);
  __builtin_nontemporal_store(o1, (f32x4*)&out[(size_t)row * CH + cb + 4]);
}

extern "C" void kernel_launch(void* const* d_in, const int* in_sizes, int n_in,
                              void* d_out, int out_size, void* d_ws, size_t ws_size,
                              hipStream_t stream) {
  const float* x        = (const float*)d_in[0];
  const float* kernel   = (const float*)d_in[1];
  const float* bias     = (const float*)d_in[2];
  const float* edge_val = (const float*)d_in[3];
  const int*   edge_row = (const int*)d_in[4];
  const int*   edge_col = (const int*)d_in[5];
  float* out = (float*)d_out;

  const int n       = in_sizes[0] / F_IN;   // 100000
  const int n_edges = in_sizes[3];          // 3200000

  // ws layout: [xwq: n*CH int8 = 12.8 MB][scale: n f32][row_ptr: (n+1) int]
  unsigned char* xwq = (unsigned char*)d_ws;
  float* scale = (float*)((char*)d_ws + (size_t)n * CH);
  int* rowptr  = (int*)((char*)d_ws + (size_t)n * CH + (size_t)n * sizeof(float));

  // Phase 1 (fused): XW = X @ W (bf16 MFMA) + int8 quant + boundary-scan rowptr
  const int GB = (n + 127) / 128;
  const int RB = (n_edges / 4 + 511) / 512;
  gemm_rowptr_fused<<<GB + RB, 512, 0, stream>>>(x, kernel, xwq, scale,
                                                 edge_row, rowptr,
                                                 n, n_edges, GB);

  // Phase 2: SpMM + bias + ReLU. 16 rows per 256-thr block (quarter-wave/row).
  const int blocks = (n * 16 + 255) / 256;
  spmm_qwave<<<blocks, 256, 0, stream>>>(xwq, scale, edge_val, edge_col,
                                         rowptr, bias, out, n);
}

// Round 16
// 107.548 us; speedup vs baseline: 1.0845x; 1.0845x over previous
//
#include <hip/hip_runtime.h>

#define F_IN 128
#define CH   128

typedef __attribute__((ext_vector_type(8))) short bf16x8;
typedef __attribute__((ext_vector_type(4))) float f32x4;
typedef __attribute__((ext_vector_type(2))) float f32x2;
typedef __attribute__((ext_vector_type(2))) unsigned u32x2;

// f32 -> bf16 round-to-nearest-even
static __device__ __forceinline__ ushort f2b(float f) {
  union { float f; unsigned u; } v; v.f = f;
  const unsigned u = v.u;
  return (ushort)((u + 0x7FFFu + ((u >> 16) & 1u)) >> 16);
}

// ---------------------------------------------------------------------------
// Phase 1 (fused): blocks [0, gemm_blocks) do XW = X @ W via bf16 MFMA,
//   then quantize each output row to int8 (offset-binary, per-node scale
//   s[r] = rowmax/127) -> 12.8 MB table + 400 KB scales. 128 rows/block.
//   Quant epilogue via wave-private LDS slab -> coalesced u32x2 stores (R11).
// blocks [gemm_blocks, ...): row_ptr boundary scan, 4 edges/thread (int4).
// mfma_f32_16x16x32_bf16 layouts (guide §3, m89-verified):
//   A frag: row = lane&15, k = (lane>>4)*8 + j
//   B frag: col = lane&15, k = (lane>>4)*8 + j
//   C/D   : col = lane&15, row = (lane>>4)*4 + reg
// ---------------------------------------------------------------------------
__global__ __launch_bounds__(512) void gemm_rowptr_fused(
    const float* __restrict__ x, const float* __restrict__ w,
    unsigned char* __restrict__ xwq, float* __restrict__ scale,
    const int* __restrict__ edge_row, int* __restrict__ row_ptr,
    int n, int n_edges, int gemm_blocks) {
  __shared__ __align__(16) ushort Wt[F_IN * CH];  // W^T, swizzled, 32 KB
  const int t = threadIdx.x;

  if ((int)blockIdx.x >= gemm_blocks) {
    // ---- rowptr tail blocks: boundary scan, 4 edges per thread ----
    const int base = (((int)blockIdx.x - gemm_blocks) * 512 + t) * 4;
    if (base < n_edges) {
      const int4 er = *(const int4*)&edge_row[base];
      const int nxt = (base + 4 < n_edges) ? edge_row[base + 4] : n;
      if (base == 0) {
        for (int r = 0; r <= er.x; ++r) row_ptr[r] = 0;
      }
      for (int r = er.x + 1; r <= er.y; ++r) row_ptr[r] = base + 1;
      for (int r = er.y + 1; r <= er.z; ++r) row_ptr[r] = base + 2;
      for (int r = er.z + 1; r <= er.w; ++r) row_ptr[r] = base + 3;
      for (int r = er.w + 1; r <= nxt;  ++r) row_ptr[r] = base + 4;
    }
    return;
  }

  // ---- GEMM blocks ----
  // stage W^T as bf16 with XOR swizzle: byte ^= (col&7)<<4
  for (int i = t; i < (F_IN * CH) / 4; i += 512) {
    const int k  = i >> 5;          // 0..127
    const int n4 = (i & 31) << 2;   // 0,4,...,124
    const f32x4 wv = *(const f32x4*)&w[k * CH + n4];
#pragma unroll
    for (int q = 0; q < 4; ++q) {
      const int nn = n4 + q;
      const int byte = (nn * 256 + k * 2) ^ ((nn & 7) << 4);
      *(ushort*)((char*)Wt + byte) = f2b(wv[q]);
    }
  }
  __syncthreads();

  const int wave = t >> 6, lane = t & 63;
  const int li   = lane & 15;
  const int kgrp = (lane >> 4) * 8;
  const int R0   = blockIdx.x * 128 + wave * 16;
  const int arow = R0 + li;

  // A fragments (4 K-steps), f32->bf16 in-register; x read-once -> nt loads
  bf16x8 a[4];
#pragma unroll
  for (int s = 0; s < 4; ++s) {
    if (arow < n) {
      const f32x4 p0 = __builtin_nontemporal_load(
          (const f32x4*)&x[arow * F_IN + s * 32 + kgrp]);
      const f32x4 p1 = __builtin_nontemporal_load(
          (const f32x4*)&x[arow * F_IN + s * 32 + kgrp + 4]);
#pragma unroll
      for (int j = 0; j < 4; ++j) {
        a[s][j]     = (short)f2b(p0[j]);
        a[s][j + 4] = (short)f2b(p1[j]);
      }
    } else {
#pragma unroll
      for (int j = 0; j < 8; ++j) a[s][j] = (short)0;
    }
  }

  f32x4 acc[8];
#pragma unroll
  for (int t8 = 0; t8 < 8; ++t8) acc[t8] = (f32x4){0.f, 0.f, 0.f, 0.f};

#pragma unroll
  for (int t8 = 0; t8 < 8; ++t8) {
    const int col = t8 * 16 + li;
#pragma unroll
    for (int s = 0; s < 4; ++s) {
      const int byte = (col * 256 + (s * 32 + kgrp) * 2) ^ ((col & 7) << 4);
      const bf16x8 b = *(const bf16x8*)((const char*)Wt + byte);
      acc[t8] = __builtin_amdgcn_mfma_f32_16x16x32_bf16(a[s], b, acc[t8], 0, 0, 0);
    }
  }

  // Epilogue A: per-row absmax (shfl over 16 channel-lanes) + scale store
  float inv4[4];
  const int r0 = R0 + (lane >> 4) * 4;
#pragma unroll
  for (int i = 0; i < 4; ++i) {
    float m = 0.f;
#pragma unroll
    for (int t8 = 0; t8 < 8; ++t8) m = fmaxf(m, fabsf(acc[t8][i]));
    m = fmaxf(m, __shfl_xor(m, 1));
    m = fmaxf(m, __shfl_xor(m, 2));
    m = fmaxf(m, __shfl_xor(m, 4));
    m = fmaxf(m, __shfl_xor(m, 8));
    inv4[i] = (m > 1e-20f) ? 127.f / m : 0.f;
    const int rr = r0 + i;
    if (rr < n && li == 0) scale[rr] = m * (1.f / 127.f);
  }

  // Epilogue B: quantize through wave-private LDS slab -> coalesced stores.
  __syncthreads();  // all waves done reading Wt; safe to reuse as byte buffer
  unsigned char* qb8 = (unsigned char*)Wt + wave * 2048;  // 16 rows x 128 B
#pragma unroll
  for (int i = 0; i < 4; ++i) {
    const int rl = (lane >> 4) * 4 + i;   // row-local 0..15
#pragma unroll
    for (int t8 = 0; t8 < 8; ++t8) {
      // |acc|*inv <= 127 by construction; +128 -> [1,255], no clamp
      const float q = rintf(acc[t8][i] * inv4[i]) + 128.f;
      qb8[rl * 128 + t8 * 16 + li] = (unsigned char)q;
    }
  }
  // wave-private region: compiler orders ds reads after writes via lgkmcnt
#pragma unroll
  for (int p = 0; p < 4; ++p) {
    const int idx = p * 64 + lane;        // 0..255
    const int rl  = idx >> 4;             // row-local 0..15
    const int off = (idx & 15) * 8;       // byte offset in row
    const int rrow = blockIdx.x * 128 + wave * 16 + rl;
    if (rrow < n) {
      const u32x2 v = *(const u32x2*)&qb8[rl * 128 + off];
      *(u32x2*)&xwq[(size_t)rrow * CH + off] = v;
    }
  }
}

// ---------------------------------------------------------------------------
// Phase 2: SpMM via global_load_lds COOPERATIVE GATHER — the one mechanism
// that gives deep gather MLP without holding results in VGPRs (R13/R14/R15:
// the register allocator refuses to hold a 32-load batch; guide m104/m108:
// global_load_lds's GLOBAL source address is per-lane -> it IS a gather,
// LDS dest = wave-uniform base + lane*16).
// Quarter-wave per row (4 rows/wave), 16-edge superblock per row:
//   * meta: lane li owns edge e0+li of its quarter's row (dummy c=0/vp=0)
//   * 8 cooperative global_load_lds, each staging 8 row-slots (2/quarter):
//     lane l serves (q=l>>4, k=i*2+((l&15)>>3), chunk=l&7), i.e. 16B of
//     row c[q][k] -> LDS wstage + i*1024 + l*16. All 8 issue back-to-back
//     with ZERO register pressure -> ~512 lane-requests in flight per wave
//     (vs ~8 compiler-limited before).
//   * s_waitcnt vmcnt(0) + sched_barrier(0) (rule #18), then decode from
//     LDS: edge (q,k) bytes [li*8,li*8+8) at (k>>1)*1024+q*256+(k&1)*128
//     +li*8 (uniform 4 req/bank = wave64-b64 minimum). f32x2 pk_fma,
//     4-edge early-exit. Lane-local epilogue (no cross-lane acc reduce).
// LDS: 4 waves x 8KB staging + slabs = ~34.5KB -> 4 blocks/CU.
// ---------------------------------------------------------------------------
#define ACCD(word, j0, vv)                                                \
  do {                                                                    \
    f32x2 lo_, hi_;                                                       \
    lo_[0] = (float)((word) & 0xFFu);                                     \
    lo_[1] = (float)(((word) >> 8) & 0xFFu);                              \
    hi_[0] = (float)(((word) >> 16) & 0xFFu);                             \
    hi_[1] = (float)((word) >> 24);                                       \
    acc2[(j0)]     = __builtin_elementwise_fma(vv, lo_, acc2[(j0)]);      \
    acc2[(j0) + 1] = __builtin_elementwise_fma(vv, hi_, acc2[(j0) + 1]);  \
  } while (0)

#define ACC8PK(U, V)                                                      \
  do {                                                                    \
    const f32x2 vv_ = {(V), (V)};                                         \
    ACCD((U)[0], 0, vv_);                                                 \
    ACCD((U)[1], 2, vv_);                                                 \
  } while (0)

__global__ __launch_bounds__(256) void spmm_glds(
    const unsigned char* __restrict__ xwq, const float* __restrict__ scale,
    const float* __restrict__ edge_val, const int* __restrict__ edge_col,
    const int* __restrict__ row_ptr, const float* __restrict__ bias,
    float* __restrict__ out, int n) {
  __shared__ __align__(16) unsigned char stage[4][8192];  // per-wave staging
  __shared__ int   cbuf[16 * 20];   // per-quarter meta slabs (16 used + 4 pad)
  __shared__ float vbuf[16 * 20];
  const int tid  = threadIdx.x;
  const int wv   = tid >> 6;
  const int lane = tid & 63;
  const int row  = (int)((blockIdx.x * 256 + tid) >> 4);
  if (row >= n) return;
  const int q     = lane >> 4;      // quarter 0..3
  const int li    = lane & 15;      // lane-in-quarter: owns ch li*8..li*8+7
  const int qslab = (tid >> 4) * 20;
  const int kk_hi = li >> 3;        // which of 2 edges this lane serves/instr
  const int chunk = lane & 7;       // 16B chunk within the 128B row
  unsigned char* wstage = stage[wv];

  const int start = row_ptr[row], end = row_ptr[row + 1];

  f32x2 acc2[4];
#pragma unroll
  for (int j = 0; j < 4; ++j) acc2[j] = (f32x2){0.f, 0.f};
  float S = 0.f;  // per-lane sum of vp (offset correction)

  for (int e0 = start; e0 < end; e0 += 16) {
    // meta: lane li owns edge e0+li of its quarter's row
    const int e = e0 + li;
    int   c_my = 0;
    float vp_my = 0.f;
    if (e < end) {
      c_my = __builtin_nontemporal_load(edge_col + e);
      vp_my = __builtin_nontemporal_load(edge_val + e) * scale[c_my];
    }
    S += vp_my;
    cbuf[qslab + li] = c_my;   // wave-private slab: in-wave DS ordering,
    vbuf[qslab + li] = vp_my;  // no barrier needed

    // 8 cooperative gathers: instr i stages 8 row-slots (2 per quarter).
    // Zero register pressure -> all 8 stay in flight simultaneously.
#pragma unroll
    for (int i = 0; i < 8; ++i) {
      const int c = cbuf[qslab + i * 2 + kk_hi];
      __builtin_amdgcn_global_load_lds(
          (const unsigned*)(xwq + (size_t)c * 128 + chunk * 16),
          (unsigned*)(wstage + i * 1024), 16, 0, 0);
    }
    asm volatile("s_waitcnt vmcnt(0)" ::: "memory");
    __builtin_amdgcn_sched_barrier(0);  // rule #18: fence reordering

    // decode from LDS: 4-edge groups, wave-uniform early exit
#pragma unroll
    for (int g4 = 0; g4 < 4; ++g4) {
      if (e0 + g4 * 4 >= end) break;
      const f32x4 v4 = *(const f32x4*)&vbuf[qslab + g4 * 4];
#pragma unroll
      for (int kk = 0; kk < 4; ++kk) {
        const int k = g4 * 4 + kk;
        const u32x2 u = *(const u32x2*)&wstage[(k >> 1) * 1024 + q * 256 +
                                               (k & 1) * 128 + li * 8];
        ACC8PK(u, v4[kk]);
      }
    }
  }

  // S over the quarter's 16 lanes (each owned distinct edges)
  S += __shfl_xor(S, 1);
  S += __shfl_xor(S, 2);
  S += __shfl_xor(S, 4);
  S += __shfl_xor(S, 8);

  // epilogue: lane-local 8 channels, bias+ReLU, direct store — no masking
  const float off = 128.f * S;
  const float* a = (const float*)acc2;
  const int cb = li * 8;
  const f32x4 b0 = *(const f32x4*)&bias[cb];
  const f32x4 b1 = *(const f32x4*)&bias[cb + 4];
  f32x4 o0, o1;
  o0[0] = fmaxf(a[0] - off + b0[0], 0.f);
  o0[1] = fmaxf(a[1] - off + b0[1], 0.f);
  o0[2] = fmaxf(a[2] - off + b0[2], 0.f);
  o0[3] = fmaxf(a[3] - off + b0[3], 0.f);
  o1[0] = fmaxf(a[4] - off + b1[0], 0.f);
  o1[1] = fmaxf(a[5] - off + b1[1], 0.f);
  o1[2] = fmaxf(a[6] - off + b1[2], 0.f);
  o1[3] = fmaxf(a[7] - off + b1[3], 0.f);
  __builtin_nontemporal_store(o0, (f32x4*)&out[(size_t)row * CH + cb]);
  __builtin_nontemporal_store(o1, (f32x4*)&out[(size_t)row * CH + cb + 4]);
}

extern "C" void kernel_launch(void* const* d_in, const int* in_sizes, int n_in,
                              void* d_out, int out_size, void* d_ws, size_t ws_size,
                              hipStream_t stream) {
  const float* x        = (const float*)d_in[0];
  const float* kernel   = (const float*)d_in[1];
  const float* bias     = (const float*)d_in[2];
  const float* edge_val = (const float*)d_in[3];
  const int*   edge_row = (const int*)d_in[4];
  const int*   edge_col = (const int*)d_in[5];
  float* out = (float*)d_out;

  const int n       = in_sizes[0] / F_IN;   // 100000
  const int n_edges = in_sizes[3];          // 3200000

  // ws layout: [xwq: n*CH int8 = 12.8 MB][scale: n f32][row_ptr: (n+1) int]
  unsigned char* xwq = (unsigned char*)d_ws;
  float* scale = (float*)((char*)d_ws + (size_t)n * CH);
  int* rowptr  = (int*)((char*)d_ws + (size_t)n * CH + (size_t)n * sizeof(float));

  // Phase 1 (fused): XW = X @ W (bf16 MFMA) + int8 quant + boundary-scan rowptr
  const int GB = (n + 127) / 128;
  const int RB = (n_edges / 4 + 511) / 512;
  gemm_rowptr_fused<<<GB + RB, 512, 0, stream>>>(x, kernel, xwq, scale,
                                                 edge_row, rowptr,
                                                 n, n_edges, GB);

  // Phase 2: SpMM + bias + ReLU. 16 rows per 256-thr block (quarter-wave/row).
  const int blocks = (n * 16 + 255) / 256;
  spmm_glds<<<blocks, 256, 0, stream>>>(xwq, scale, edge_val, edge_col,
                                        rowptr, bias, out, n);
}